// Round 14
// baseline (537.729 us; speedup 1.0000x reference)
//
#include <hip/hip_runtime.h>
#include <math.h>

#define BB 2
#define NN 40960
#define KK 16

typedef float v2f __attribute__((ext_vector_type(2)));
typedef _Float16 h16;
typedef h16 h16x2 __attribute__((ext_vector_type(2)));

__device__ __forceinline__ v2f fma2(v2f a, v2f b, v2f c){
  return __builtin_elementwise_fma(a, b, c);
}
__device__ __forceinline__ v2f mk2(float a, float b){ v2f r; r.x=a; r.y=b; return r; }

#if __has_builtin(__builtin_amdgcn_fdot2)
__device__ __forceinline__ float dot2acc(h16x2 w, h16x2 f, float acc){
  return __builtin_amdgcn_fdot2(w, f, acc, false);
}
#else
__device__ __forceinline__ float dot2acc(h16x2 w, h16x2 f, float acc){
  return acc + (float)w.x*(float)f.x + (float)w.y*(float)f.y;
}
#endif
#if __has_builtin(__builtin_amdgcn_exp2f)
__device__ __forceinline__ float exp2fast(float x){ return __builtin_amdgcn_exp2f(x); }
#else
__device__ __forceinline__ float exp2fast(float x){ return __expf(x*0.6931471805599453f); }
#endif
#if __has_builtin(__builtin_amdgcn_cvt_pkrtz)
__device__ __forceinline__ h16x2 pkh(float a, float b){
  return __builtin_bit_cast(h16x2, __builtin_amdgcn_cvt_pkrtz(a,b));
}
#else
__device__ __forceinline__ h16x2 pkh(float a, float b){ h16x2 r; r.x=(h16)a; r.y=(h16)b; return r; }
#endif

// ---- 16-lane sum on the VALU pipe via DPP ----
template<int CTRL>
__device__ __forceinline__ float dppf(float x){
  return __int_as_float(__builtin_amdgcn_update_dpp(0, __float_as_int(x), CTRL, 0xF, 0xF, true));
}
__device__ __forceinline__ float red16_sum(float v){
  v += dppf<0xB1>(v);    // quad_perm:[1,0,3,2]  (xor 1)
  v += dppf<0x4E>(v);    // quad_perm:[2,3,0,1]  (xor 2)
  v += dppf<0x141>(v);   // row_half_mirror      (xor 4 equiv)
  v += dppf<0x140>(v);   // row_mirror           (xor 8 equiv)
  return v;
}

// ---- pre-processed weights (f16 for dot2 paths, f32 elsewhere) ----
__device__ alignas(16) float g_pw1[32*10];
__device__ alignas(16) float g_pb1[32];
__device__ alignas(16) h16x2 g_w2h[32*16];   // mlp2 folded, f16 pairs
__device__ alignas(16) float g_pb2[32];
__device__ alignas(16) h16x2 g_fch1[64*32];  // fc1 * log2e, f16 pairs
__device__ alignas(16) float g_fcb1s[64];    // fc1 bias * log2e
__device__ alignas(16) h16x2 g_fch2[64*32];  // fc2 * log2e, f16 pairs
__device__ alignas(16) float g_fcb2s[64];
__device__ alignas(16) float g_pcw[32*64];   // ap1 mlp folded (f32)
__device__ alignas(16) float g_pcb[32];
__device__ alignas(16) float g_pdw[64*64];   // ap2 mlp folded (f32)
__device__ alignas(16) float g_pdb[64];

#define LOG2E 1.44269504088896f

// Fused: feature transpose (blocks 0..319) + weight prep (last block)
__global__ __launch_bounds__(256) void k_pre(
  const float* __restrict__ feat, float* __restrict__ feat_t,
  const float* __restrict__ w1, const float* __restrict__ b1,
  const float* __restrict__ g1, const float* __restrict__ be1, const float* __restrict__ m1, const float* __restrict__ v1,
  const float* __restrict__ fc1w, const float* __restrict__ fc1b,
  const float* __restrict__ cw, const float* __restrict__ cb,
  const float* __restrict__ cg, const float* __restrict__ cbe, const float* __restrict__ cm, const float* __restrict__ cv,
  const float* __restrict__ w2, const float* __restrict__ b2,
  const float* __restrict__ g2, const float* __restrict__ be2, const float* __restrict__ m2, const float* __restrict__ v2,
  const float* __restrict__ fc2w, const float* __restrict__ fc2b,
  const float* __restrict__ dw, const float* __restrict__ db,
  const float* __restrict__ dg, const float* __restrict__ dbe, const float* __restrict__ dm, const float* __restrict__ dv)
{
  int tid = threadIdx.x;
  int bid = blockIdx.x;
  if (bid < BB*NN/256){
    int b = bid / (NN/256);
    int n = (bid % (NN/256))*256 + tid;
    float v[32];
    #pragma unroll
    for (int h=0; h<32; ++h) v[h] = feat[((size_t)(b*32+h))*NN + n];
    float* o = feat_t + ((size_t)b*NN + n)*32;
    #pragma unroll
    for (int h=0; h<32; h+=4){ *(float4*)(o+h) = make_float4(v[h],v[h+1],v[h+2],v[h+3]); }
    return;
  }
  for (int i=tid; i<320; i+=256){ int h=i/10;
    g_pw1[i] = w1[i] * (g1[h]*rsqrtf(v1[h]+1e-5f)); }
  if (tid<32){ float s=g1[tid]*rsqrtf(v1[tid]+1e-5f);
    g_pb1[tid] = (b1[tid]-m1[tid])*s+be1[tid]; }
  for (int i=tid; i<512; i+=256){ int h=i>>4, c=i&15;
    float s=g2[h]*rsqrtf(v2[h]+1e-5f);
    g_w2h[i] = pkh(w2[h*32+2*c]*s, w2[h*32+2*c+1]*s); }
  if (tid<32){ float s=g2[tid]*rsqrtf(v2[tid]+1e-5f);
    g_pb2[tid] = (b2[tid]-m2[tid])*s+be2[tid]; }
  for (int i=tid; i<2048; i+=256){ int o=i>>5, c=i&31;
    g_fch1[i] = pkh(fc1w[o*64+2*c]*LOG2E, fc1w[o*64+2*c+1]*LOG2E);
    g_fch2[i] = pkh(fc2w[o*64+2*c]*LOG2E, fc2w[o*64+2*c+1]*LOG2E); }
  if (tid<64){ g_fcb1s[tid] = fc1b[tid]*LOG2E; g_fcb2s[tid] = fc2b[tid]*LOG2E; }
  for (int i=tid; i<2048; i+=256){ int h=i>>6;
    g_pcw[i] = cw[i] * (cg[h]*rsqrtf(cv[h]+1e-5f)); }
  if (tid<32){ float s=cg[tid]*rsqrtf(cv[tid]+1e-5f);
    g_pcb[tid] = (cb[tid]-cm[tid])*s+cbe[tid]; }
  for (int i=tid; i<4096; i+=256){ int h=i>>6;
    g_pdw[i] = dw[i] * (dg[h]*rsqrtf(dv[h]+1e-5f)); }
  if (tid<64){ float s=dg[tid]*rsqrtf(dv[tid]+1e-5f);
    g_pdb[tid] = (db[tid]-dm[tid])*s+dbe[tid]; }
}

// Dual-point: thread handles points n (A) and n+4 (B); one uniform weight
// stream feeds two independent dot2/DPP chains (f16 state -> fits registers).
__global__ __launch_bounds__(256,2) void k_stage1(
  const float* __restrict__ xyz, const float* __restrict__ feat_t, const int* __restrict__ nidx,
  float* __restrict__ fagg)
{
  int tid = threadIdx.x;
  int lane = tid & 63, wvv = tid >> 6;
  int k = lane & 15, ns = lane >> 4;
  int b = blockIdx.x / (NN/32);
  int n = (blockIdx.x % (NN/32))*32 + wvv*8 + ns;
  size_t bnA = (size_t)b*NN + n, bnB = bnA + 4;
  int idxA = nidx[bnA*KK + k];
  int idxB = nidx[bnB*KK + k];

  // gathers first (f_nb -> f16 pairs, channels 0..31)
  h16x2 hA[32], hB[32];
  {
    const float* fa = feat_t + ((size_t)b*NN + idxA)*32;
    const float* fbp = feat_t + ((size_t)b*NN + idxB)*32;
    #pragma unroll
    for (int h=0; h<32; h+=4){
      float4 xa = *(const float4*)(fa+h);
      float4 xb = *(const float4*)(fbp+h);
      hA[h>>1] = pkh(xa.x,xa.y); hA[(h>>1)+1] = pkh(xa.z,xa.w);
      hB[h>>1] = pkh(xb.x,xb.y); hB[(h>>1)+1] = pkh(xb.z,xb.w);
    }
  }
  v2f eA[5], eB[5];
  {
    const float* tp = xyz + bnA*3; const float* qp = xyz + ((size_t)b*NN + idxA)*3;
    float t0=tp[0],t1=tp[1],t2=tp[2], q0=qp[0],q1=qp[1],q2=qp[2];
    float r0=t0-q0,r1=t1-q1,r2=t2-q2;
    eA[0]=mk2(sqrtf(r0*r0+r1*r1+r2*r2),r0); eA[1]=mk2(r1,r2);
    eA[2]=mk2(t0,t1); eA[3]=mk2(t2,q0); eA[4]=mk2(q1,q2);
  }
  {
    const float* tp = xyz + bnB*3; const float* qp = xyz + ((size_t)b*NN + idxB)*3;
    float t0=tp[0],t1=tp[1],t2=tp[2], q0=qp[0],q1=qp[1],q2=qp[2];
    float r0=t0-q0,r1=t1-q1,r2=t2-q2;
    eB[0]=mk2(sqrtf(r0*r0+r1*r1+r2*r2),r0); eB[1]=mk2(r1,r2);
    eB[2]=mk2(t0,t1); eB[3]=mk2(t2,q0); eB[4]=mk2(q1,q2);
  }
  // mlp1 (10->32, fp32, shared weight stream) -> f16 pairs, channels 32..63
  #pragma unroll
  for (int h=0; h<32; h+=2){
    const v2f* w0 = (const v2f*)(g_pw1 + h*10);
    const v2f* w1 = (const v2f*)(g_pw1 + (h+1)*10);
    v2f aA0=mk2(g_pb1[h],0.f), aA1=mk2(g_pb1[h+1],0.f);
    v2f aB0=mk2(g_pb1[h],0.f), aB1=mk2(g_pb1[h+1],0.f);
    #pragma unroll
    for (int c=0; c<5; ++c){
      aA0=fma2(w0[c],eA[c],aA0); aA1=fma2(w1[c],eA[c],aA1);
      aB0=fma2(w0[c],eB[c],aB0); aB1=fma2(w1[c],eB[c],aB1);
    }
    hA[16+(h>>1)] = pkh(fmaxf(aA0.x+aA0.y,0.f), fmaxf(aA1.x+aA1.y,0.f));
    hB[16+(h>>1)] = pkh(fmaxf(aB0.x+aB0.y,0.f), fmaxf(aB1.x+aB1.y,0.f));
  }

  // fc1 (dot2, weights*log2e) + relu + exp2-softmax + agg — 8 chains/iter
  float spA[4], sfA[4], spB[4], sfB[4];
  #pragma unroll
  for (int ob=0; ob<64; ob+=4){
    const h16x2* w0 = &g_fch1[(ob+0)*32];
    const h16x2* w1p = &g_fch1[(ob+1)*32];
    const h16x2* w2p = &g_fch1[(ob+2)*32];
    const h16x2* w3p = &g_fch1[(ob+3)*32];
    float aA0=g_fcb1s[ob+0], aA1=g_fcb1s[ob+1], aA2=g_fcb1s[ob+2], aA3=g_fcb1s[ob+3];
    float aB0=aA0, aB1=aA1, aB2=aA2, aB3=aA3;
    #pragma unroll
    for (int c=0; c<32; ++c){
      h16x2 fA = hA[c], fB = hB[c];
      aA0 = dot2acc(w0[c], fA, aA0); aA1 = dot2acc(w1p[c], fA, aA1);
      aA2 = dot2acc(w2p[c], fA, aA2); aA3 = dot2acc(w3p[c], fA, aA3);
      aB0 = dot2acc(w0[c], fB, aB0); aB1 = dot2acc(w1p[c], fB, aB1);
      aB2 = dot2acc(w2p[c], fB, aB2); aB3 = dot2acc(w3p[c], fB, aB3);
    }
    float pA0=exp2fast(fmaxf(aA0,0.f)), pA1=exp2fast(fmaxf(aA1,0.f));
    float pA2=exp2fast(fmaxf(aA2,0.f)), pA3=exp2fast(fmaxf(aA3,0.f));
    float pB0=exp2fast(fmaxf(aB0,0.f)), pB1=exp2fast(fmaxf(aB1,0.f));
    float pB2=exp2fast(fmaxf(aB2,0.f)), pB3=exp2fast(fmaxf(aB3,0.f));
    float fA0=(float)hA[(ob>>1)+0].x, fA1=(float)hA[(ob>>1)+0].y;
    float fA2=(float)hA[(ob>>1)+1].x, fA3=(float)hA[(ob>>1)+1].y;
    float fB0=(float)hB[(ob>>1)+0].x, fB1=(float)hB[(ob>>1)+0].y;
    float fB2=(float)hB[(ob>>1)+1].x, fB3=(float)hB[(ob>>1)+1].y;
    float sA0=red16_sum(pA0), sA1=red16_sum(pA1), sA2=red16_sum(pA2), sA3=red16_sum(pA3);
    float sB0=red16_sum(pB0), sB1=red16_sum(pB1), sB2=red16_sum(pB2), sB3=red16_sum(pB3);
    float tA0=red16_sum(fA0*pA0), tA1=red16_sum(fA1*pA1);
    float tA2=red16_sum(fA2*pA2), tA3=red16_sum(fA3*pA3);
    float tB0=red16_sum(fB0*pB0), tB1=red16_sum(fB1*pB1);
    float tB2=red16_sum(fB2*pB2), tB3=red16_sum(fB3*pB3);
    if ((ob>>2)==k){
      spA[0]=sA0; spA[1]=sA1; spA[2]=sA2; spA[3]=sA3;
      sfA[0]=tA0; sfA[1]=tA1; sfA[2]=tA2; sfA[3]=tA3;
      spB[0]=sB0; spB[1]=sB1; spB[2]=sB2; spB[3]=sB3;
      sfB[0]=tB0; sfB[1]=tB1; sfB[2]=tB2; sfB[3]=tB3;
    }
  }
  v2f a01A = mk2(__fdividef(sfA[0],spA[0]), __fdividef(sfA[1],spA[1]));
  v2f a23A = mk2(__fdividef(sfA[2],spA[2]), __fdividef(sfA[3],spA[3]));
  v2f a01B = mk2(__fdividef(sfB[0],spB[0]), __fdividef(sfB[1],spB[1]));
  v2f a23B = mk2(__fdividef(sfB[2],spB[2]), __fdividef(sfB[3],spB[3]));

  // ap1 mlp (64->32, fp32, shared weight stream)
  float o0A=0.f,o1A=0.f,o0B=0.f,o1B=0.f;
  #pragma unroll
  for (int h=0; h<32; h+=2){
    const v2f* wr0 = (const v2f*)(g_pcw + h*64 + 4*k);
    const v2f* wr1 = (const v2f*)(g_pcw + (h+1)*64 + 4*k);
    v2f pA0 = fma2(wr0[0], a01A, wr0[1]*a23A);
    v2f pA1 = fma2(wr1[0], a01A, wr1[1]*a23A);
    v2f pB0 = fma2(wr0[0], a01B, wr0[1]*a23B);
    v2f pB1 = fma2(wr1[0], a01B, wr1[1]*a23B);
    float rA0 = red16_sum(pA0.x + pA0.y);
    float rA1 = red16_sum(pA1.x + pA1.y);
    float rB0 = red16_sum(pB0.x + pB0.y);
    float rB1 = red16_sum(pB1.x + pB1.y);
    float vA0 = fmaxf(rA0 + g_pcb[h], 0.f);
    float vA1 = fmaxf(rA1 + g_pcb[h+1], 0.f);
    float vB0 = fmaxf(rB0 + g_pcb[h], 0.f);
    float vB1 = fmaxf(rB1 + g_pcb[h+1], 0.f);
    if ((h&15)==k){ if (h<16){ o0A=vA0; o0B=vB0; } else { o1A=vA0; o1B=vB0; } }
    if (((h+1)&15)==k){ if (h+1<16){ o0A=vA1; o0B=vB1; } else { o1A=vA1; o1B=vB1; } }
  }
  float* foA = fagg + bnA*32;
  float* foB = fagg + bnB*32;
  foA[k]=o0A; foA[k+16]=o1A;
  foB[k]=o0B; foB[k+16]=o1B;
}

__global__ __launch_bounds__(256,2) void k_stage2(
  const float* __restrict__ xyz, const float* __restrict__ fagg, const int* __restrict__ nidx,
  float* __restrict__ outp)
{
  int tid = threadIdx.x;
  int lane = tid & 63, wvv = tid >> 6;
  int k = lane & 15, ns = lane >> 4;
  int b = blockIdx.x / (NN/32);
  int n = (blockIdx.x % (NN/32))*32 + wvv*8 + ns;
  size_t bnA = (size_t)b*NN + n, bnB = bnA + 4;
  int idxA = nidx[bnA*KK + k];
  int idxB = nidx[bnB*KK + k];

  // gathers first (fagg rows -> f16 pairs, channels 0..31)
  h16x2 hA[32], hB[32];
  {
    const float* fa = fagg + ((size_t)b*NN + idxA)*32;
    const float* fbp = fagg + ((size_t)b*NN + idxB)*32;
    #pragma unroll
    for (int h=0; h<32; h+=4){
      float4 xa = *(const float4*)(fa+h);
      float4 xb = *(const float4*)(fbp+h);
      hA[h>>1] = pkh(xa.x,xa.y); hA[(h>>1)+1] = pkh(xa.z,xa.w);
      hB[h>>1] = pkh(xb.x,xb.y); hB[(h>>1)+1] = pkh(xb.z,xb.w);
    }
  }
  v2f eA[5], eB[5];
  {
    const float* tp = xyz + bnA*3; const float* qp = xyz + ((size_t)b*NN + idxA)*3;
    float t0=tp[0],t1=tp[1],t2=tp[2], q0=qp[0],q1=qp[1],q2=qp[2];
    float r0=t0-q0,r1=t1-q1,r2=t2-q2;
    eA[0]=mk2(sqrtf(r0*r0+r1*r1+r2*r2),r0); eA[1]=mk2(r1,r2);
    eA[2]=mk2(t0,t1); eA[3]=mk2(t2,q0); eA[4]=mk2(q1,q2);
  }
  {
    const float* tp = xyz + bnB*3; const float* qp = xyz + ((size_t)b*NN + idxB)*3;
    float t0=tp[0],t1=tp[1],t2=tp[2], q0=qp[0],q1=qp[1],q2=qp[2];
    float r0=t0-q0,r1=t1-q1,r2=t2-q2;
    eB[0]=mk2(sqrtf(r0*r0+r1*r1+r2*r2),r0); eB[1]=mk2(r1,r2);
    eB[2]=mk2(t0,t1); eB[3]=mk2(t2,q0); eB[4]=mk2(q1,q2);
  }
  // mlp1 (fp32, shared weights) -> f16 pairs hx
  h16x2 hxA[16], hxB[16];
  #pragma unroll
  for (int h=0; h<32; h+=2){
    const v2f* w0 = (const v2f*)(g_pw1 + h*10);
    const v2f* w1 = (const v2f*)(g_pw1 + (h+1)*10);
    v2f aA0=mk2(g_pb1[h],0.f), aA1=mk2(g_pb1[h+1],0.f);
    v2f aB0=mk2(g_pb1[h],0.f), aB1=mk2(g_pb1[h+1],0.f);
    #pragma unroll
    for (int c=0; c<5; ++c){
      aA0=fma2(w0[c],eA[c],aA0); aA1=fma2(w1[c],eA[c],aA1);
      aB0=fma2(w0[c],eB[c],aB0); aB1=fma2(w1[c],eB[c],aB1);
    }
    hxA[h>>1] = pkh(fmaxf(aA0.x+aA0.y,0.f), fmaxf(aA1.x+aA1.y,0.f));
    hxB[h>>1] = pkh(fmaxf(aB0.x+aB0.y,0.f), fmaxf(aB1.x+aB1.y,0.f));
  }
  // mlp2 (32->32 via dot2, shared weight stream) -> channels 32..63
  #pragma unroll
  for (int h=0; h<32; h+=2){
    const h16x2* wr0 = &g_w2h[(h+0)*16];
    const h16x2* wr1 = &g_w2h[(h+1)*16];
    float aA0 = g_pb2[h+0], aA1 = g_pb2[h+1];
    float aB0 = aA0, aB1 = aA1;
    #pragma unroll
    for (int c=0; c<16; ++c){
      h16x2 fA=hxA[c], fB=hxB[c];
      aA0=dot2acc(wr0[c],fA,aA0); aA1=dot2acc(wr1[c],fA,aA1);
      aB0=dot2acc(wr0[c],fB,aB0); aB1=dot2acc(wr1[c],fB,aB1);
    }
    hA[16+(h>>1)] = pkh(fmaxf(aA0,0.f), fmaxf(aA1,0.f));
    hB[16+(h>>1)] = pkh(fmaxf(aB0,0.f), fmaxf(aB1,0.f));
  }

  // fc2 (dot2) + exp2-softmax + agg — 8 chains/iter
  float spA[4], sfA[4], spB[4], sfB[4];
  #pragma unroll
  for (int ob=0; ob<64; ob+=4){
    const h16x2* w0 = &g_fch2[(ob+0)*32];
    const h16x2* w1p = &g_fch2[(ob+1)*32];
    const h16x2* w2p = &g_fch2[(ob+2)*32];
    const h16x2* w3p = &g_fch2[(ob+3)*32];
    float aA0=g_fcb2s[ob+0], aA1=g_fcb2s[ob+1], aA2=g_fcb2s[ob+2], aA3=g_fcb2s[ob+3];
    float aB0=aA0, aB1=aA1, aB2=aA2, aB3=aA3;
    #pragma unroll
    for (int c=0; c<32; ++c){
      h16x2 fA = hA[c], fB = hB[c];
      aA0 = dot2acc(w0[c], fA, aA0); aA1 = dot2acc(w1p[c], fA, aA1);
      aA2 = dot2acc(w2p[c], fA, aA2); aA3 = dot2acc(w3p[c], fA, aA3);
      aB0 = dot2acc(w0[c], fB, aB0); aB1 = dot2acc(w1p[c], fB, aB1);
      aB2 = dot2acc(w2p[c], fB, aB2); aB3 = dot2acc(w3p[c], fB, aB3);
    }
    float pA0=exp2fast(fmaxf(aA0,0.f)), pA1=exp2fast(fmaxf(aA1,0.f));
    float pA2=exp2fast(fmaxf(aA2,0.f)), pA3=exp2fast(fmaxf(aA3,0.f));
    float pB0=exp2fast(fmaxf(aB0,0.f)), pB1=exp2fast(fmaxf(aB1,0.f));
    float pB2=exp2fast(fmaxf(aB2,0.f)), pB3=exp2fast(fmaxf(aB3,0.f));
    float fA0=(float)hA[(ob>>1)+0].x, fA1=(float)hA[(ob>>1)+0].y;
    float fA2=(float)hA[(ob>>1)+1].x, fA3=(float)hA[(ob>>1)+1].y;
    float fB0=(float)hB[(ob>>1)+0].x, fB1=(float)hB[(ob>>1)+0].y;
    float fB2=(float)hB[(ob>>1)+1].x, fB3=(float)hB[(ob>>1)+1].y;
    float sA0=red16_sum(pA0), sA1=red16_sum(pA1), sA2=red16_sum(pA2), sA3=red16_sum(pA3);
    float sB0=red16_sum(pB0), sB1=red16_sum(pB1), sB2=red16_sum(pB2), sB3=red16_sum(pB3);
    float tA0=red16_sum(fA0*pA0), tA1=red16_sum(fA1*pA1);
    float tA2=red16_sum(fA2*pA2), tA3=red16_sum(fA3*pA3);
    float tB0=red16_sum(fB0*pB0), tB1=red16_sum(fB1*pB1);
    float tB2=red16_sum(fB2*pB2), tB3=red16_sum(fB3*pB3);
    if ((ob>>2)==k){
      spA[0]=sA0; spA[1]=sA1; spA[2]=sA2; spA[3]=sA3;
      sfA[0]=tA0; sfA[1]=tA1; sfA[2]=tA2; sfA[3]=tA3;
      spB[0]=sB0; spB[1]=sB1; spB[2]=sB2; spB[3]=sB3;
      sfB[0]=tB0; sfB[1]=tB1; sfB[2]=tB2; sfB[3]=tB3;
    }
  }
  v2f a01A = mk2(__fdividef(sfA[0],spA[0]), __fdividef(sfA[1],spA[1]));
  v2f a23A = mk2(__fdividef(sfA[2],spA[2]), __fdividef(sfA[3],spA[3]));
  v2f a01B = mk2(__fdividef(sfB[0],spB[0]), __fdividef(sfB[1],spB[1]));
  v2f a23B = mk2(__fdividef(sfB[2],spB[2]), __fdividef(sfB[3],spB[3]));

  // ap2 mlp (64->64, fp32, shared weight stream) -> outputs for both points
  float o4A[4], o4B[4];
  #pragma unroll
  for (int h=0; h<64; h+=2){
    const v2f* wr0 = (const v2f*)(g_pdw + h*64 + 4*k);
    const v2f* wr1 = (const v2f*)(g_pdw + (h+1)*64 + 4*k);
    v2f pA0 = fma2(wr0[0], a01A, wr0[1]*a23A);
    v2f pA1 = fma2(wr1[0], a01A, wr1[1]*a23A);
    v2f pB0 = fma2(wr0[0], a01B, wr0[1]*a23B);
    v2f pB1 = fma2(wr1[0], a01B, wr1[1]*a23B);
    float rA0 = red16_sum(pA0.x + pA0.y);
    float rA1 = red16_sum(pA1.x + pA1.y);
    float rB0 = red16_sum(pB0.x + pB0.y);
    float rB1 = red16_sum(pB1.x + pB1.y);
    float vA0 = fmaxf(rA0 + g_pdb[h], 0.f);
    float vA1 = fmaxf(rA1 + g_pdb[h+1], 0.f);
    float vB0 = fmaxf(rB0 + g_pdb[h], 0.f);
    float vB1 = fmaxf(rB1 + g_pdb[h+1], 0.f);
    if ((h&15)==k){ o4A[h>>4]=vA0; o4B[h>>4]=vB0; }
    if (((h+1)&15)==k){ o4A[(h+1)>>4]=vA1; o4B[(h+1)>>4]=vB1; }
  }
  #pragma unroll
  for (int j=0; j<4; ++j){
    outp[((size_t)(b*64 + k + 16*j))*NN + n]     = o4A[j];
    outp[((size_t)(b*64 + k + 16*j))*NN + n + 4] = o4B[j];
  }
}

extern "C" void kernel_launch(void* const* d_in, const int* in_sizes, int n_in,
                              void* d_out, int out_size, void* d_ws, size_t ws_size,
                              hipStream_t stream){
  const float* xyz     = (const float*)d_in[0];
  const float* feature = (const float*)d_in[1];
  const int*   nidx    = (const int*)d_in[30];
  float* feat_t = (float*)d_ws;                       // (B,N,32)
  float* fagg   = feat_t + (size_t)BB*NN*32;          // (B,N,32)

  k_pre<<<BB*NN/256 + 1, 256, 0, stream>>>(feature, feat_t,
    (const float*)d_in[2],(const float*)d_in[3],(const float*)d_in[4],(const float*)d_in[5],
    (const float*)d_in[6],(const float*)d_in[7],
    (const float*)d_in[8],(const float*)d_in[9],
    (const float*)d_in[10],(const float*)d_in[11],(const float*)d_in[12],(const float*)d_in[13],
    (const float*)d_in[14],(const float*)d_in[15],
    (const float*)d_in[16],(const float*)d_in[17],(const float*)d_in[18],(const float*)d_in[19],
    (const float*)d_in[20],(const float*)d_in[21],
    (const float*)d_in[22],(const float*)d_in[23],
    (const float*)d_in[24],(const float*)d_in[25],(const float*)d_in[26],(const float*)d_in[27],
    (const float*)d_in[28],(const float*)d_in[29]);
  k_stage1<<<BB*NN/32, 256, 0, stream>>>(xyz, feat_t, nidx, fagg);
  k_stage2<<<BB*NN/32, 256, 0, stream>>>(xyz, fagg, nidx, (float*)d_out);
}

// Round 15
// 407.648 us; speedup vs baseline: 1.3191x; 1.3191x over previous
//
#include <hip/hip_runtime.h>
#include <math.h>

#define BB 2
#define NN 40960
#define KK 16

typedef float v2f __attribute__((ext_vector_type(2)));
typedef _Float16 h16;
typedef h16 h16x2 __attribute__((ext_vector_type(2)));

__device__ __forceinline__ v2f fma2(v2f a, v2f b, v2f c){
  return __builtin_elementwise_fma(a, b, c);
}
__device__ __forceinline__ v2f mk2(float a, float b){ v2f r; r.x=a; r.y=b; return r; }

#if __has_builtin(__builtin_amdgcn_fdot2)
__device__ __forceinline__ float dot2acc(h16x2 w, h16x2 f, float acc){
  return __builtin_amdgcn_fdot2(w, f, acc, false);
}
#else
__device__ __forceinline__ float dot2acc(h16x2 w, h16x2 f, float acc){
  return acc + (float)w.x*(float)f.x + (float)w.y*(float)f.y;
}
#endif
#if __has_builtin(__builtin_amdgcn_exp2f)
__device__ __forceinline__ float exp2fast(float x){ return __builtin_amdgcn_exp2f(x); }
#else
__device__ __forceinline__ float exp2fast(float x){ return __expf(x*0.6931471805599453f); }
#endif
#if __has_builtin(__builtin_amdgcn_cvt_pkrtz)
__device__ __forceinline__ h16x2 pkh(float a, float b){
  return __builtin_bit_cast(h16x2, __builtin_amdgcn_cvt_pkrtz(a,b));
}
#else
__device__ __forceinline__ h16x2 pkh(float a, float b){ h16x2 r; r.x=(h16)a; r.y=(h16)b; return r; }
#endif

// ---- 16-lane sum on the VALU pipe via DPP ----
template<int CTRL>
__device__ __forceinline__ float dppf(float x){
  return __int_as_float(__builtin_amdgcn_update_dpp(0, __float_as_int(x), CTRL, 0xF, 0xF, true));
}
__device__ __forceinline__ float red16_sum(float v){
  v += dppf<0xB1>(v);    // quad_perm:[1,0,3,2]  (xor 1)
  v += dppf<0x4E>(v);    // quad_perm:[2,3,0,1]  (xor 2)
  v += dppf<0x141>(v);   // row_half_mirror      (xor 4 equiv)
  v += dppf<0x140>(v);   // row_mirror           (xor 8 equiv)
  return v;
}
// intra-wave LDS producer->consumer fence (no cross-wave LDS sharing)
__device__ __forceinline__ void wave_sync(){
  asm volatile("s_waitcnt lgkmcnt(0)" ::: "memory");
  __builtin_amdgcn_sched_barrier(0);
}

// ---- pre-processed weights (f16 for dot2 paths, f32 elsewhere) ----
__device__ alignas(16) float g_pw1[32*10];
__device__ alignas(16) float g_pb1[32];
__device__ alignas(16) h16x2 g_w2h[32*16];   // mlp2 folded, f16 pairs
__device__ alignas(16) float g_pb2[32];
__device__ alignas(16) h16x2 g_fch1[64*32];  // fc1 * log2e, f16 pairs
__device__ alignas(16) float g_fcb1s[64];    // fc1 bias * log2e
__device__ alignas(16) h16x2 g_fch2[64*32];  // fc2 * log2e, f16 pairs
__device__ alignas(16) float g_fcb2s[64];
__device__ alignas(16) h16x2 g_cwh[32*32];   // ap1 mlp folded, f16 pairs (row-major)
__device__ alignas(16) float g_pcb[32];
__device__ alignas(16) h16x2 g_dwh[64*32];   // ap2 mlp folded, f16 pairs (row-major)
__device__ alignas(16) float g_pdb[64];

#define LOG2E 1.44269504088896f

// Fused: feature transpose (blocks 0..319) + weight prep (last block)
__global__ __launch_bounds__(256) void k_pre(
  const float* __restrict__ feat, float* __restrict__ feat_t,
  const float* __restrict__ w1, const float* __restrict__ b1,
  const float* __restrict__ g1, const float* __restrict__ be1, const float* __restrict__ m1, const float* __restrict__ v1,
  const float* __restrict__ fc1w, const float* __restrict__ fc1b,
  const float* __restrict__ cw, const float* __restrict__ cb,
  const float* __restrict__ cg, const float* __restrict__ cbe, const float* __restrict__ cm, const float* __restrict__ cv,
  const float* __restrict__ w2, const float* __restrict__ b2,
  const float* __restrict__ g2, const float* __restrict__ be2, const float* __restrict__ m2, const float* __restrict__ v2,
  const float* __restrict__ fc2w, const float* __restrict__ fc2b,
  const float* __restrict__ dw, const float* __restrict__ db,
  const float* __restrict__ dg, const float* __restrict__ dbe, const float* __restrict__ dm, const float* __restrict__ dv)
{
  int tid = threadIdx.x;
  int bid = blockIdx.x;
  if (bid < BB*NN/256){
    int b = bid / (NN/256);
    int n = (bid % (NN/256))*256 + tid;
    float v[32];
    #pragma unroll
    for (int h=0; h<32; ++h) v[h] = feat[((size_t)(b*32+h))*NN + n];
    float* o = feat_t + ((size_t)b*NN + n)*32;
    #pragma unroll
    for (int h=0; h<32; h+=4){ *(float4*)(o+h) = make_float4(v[h],v[h+1],v[h+2],v[h+3]); }
    return;
  }
  for (int i=tid; i<320; i+=256){ int h=i/10;
    g_pw1[i] = w1[i] * (g1[h]*rsqrtf(v1[h]+1e-5f)); }
  if (tid<32){ float s=g1[tid]*rsqrtf(v1[tid]+1e-5f);
    g_pb1[tid] = (b1[tid]-m1[tid])*s+be1[tid]; }
  for (int i=tid; i<512; i+=256){ int h=i>>4, c=i&15;
    float s=g2[h]*rsqrtf(v2[h]+1e-5f);
    g_w2h[i] = pkh(w2[h*32+2*c]*s, w2[h*32+2*c+1]*s); }
  if (tid<32){ float s=g2[tid]*rsqrtf(v2[tid]+1e-5f);
    g_pb2[tid] = (b2[tid]-m2[tid])*s+be2[tid]; }
  for (int i=tid; i<2048; i+=256){ int o=i>>5, c=i&31;
    g_fch1[i] = pkh(fc1w[o*64+2*c]*LOG2E, fc1w[o*64+2*c+1]*LOG2E);
    g_fch2[i] = pkh(fc2w[o*64+2*c]*LOG2E, fc2w[o*64+2*c+1]*LOG2E); }
  if (tid<64){ g_fcb1s[tid] = fc1b[tid]*LOG2E; g_fcb2s[tid] = fc2b[tid]*LOG2E; }
  // ap1 folded -> f16 pairs (row-major: row h, 32 pairs)
  for (int i=tid; i<1024; i+=256){ int h=i>>5, c=i&31;
    float s=cg[h]*rsqrtf(cv[h]+1e-5f);
    g_cwh[i] = pkh(cw[h*64+2*c]*s, cw[h*64+2*c+1]*s); }
  if (tid<32){ float s=cg[tid]*rsqrtf(cv[tid]+1e-5f);
    g_pcb[tid] = (cb[tid]-cm[tid])*s+cbe[tid]; }
  // ap2 folded -> f16 pairs
  for (int i=tid; i<2048; i+=256){ int o=i>>5, c=i&31;
    float s=dg[o]*rsqrtf(dv[o]+1e-5f);
    g_dwh[i] = pkh(dw[o*64+2*c]*s, dw[o*64+2*c+1]*s); }
  if (tid<64){ float s=dg[tid]*rsqrtf(dv[tid]+1e-5f);
    g_pdb[tid] = (db[tid]-dm[tid])*s+dbe[tid]; }
}

__global__ __launch_bounds__(256,2) void k_stage1(
  const float* __restrict__ xyz, const float* __restrict__ feat_t, const int* __restrict__ nidx,
  float* __restrict__ fagg)
{
  __shared__ float s_agg[4][4][64];   // [wave][group(point)][64 agg] = 4KB
  int tid = threadIdx.x;
  int lane = tid & 63, wvv = tid >> 6;
  int k = lane & 15, ns = lane >> 4;
  int b = blockIdx.x / (NN/16);
  int n = (blockIdx.x % (NN/16))*16 + wvv*4 + ns;
  size_t bn = (size_t)b*NN + n;
  int idxv = nidx[bn*KK + k];

  // scattered gathers first; latency hides under mlp1 (f_nb -> f16, ch 0..31)
  h16x2 h2[32];
  {
    const float* fb = feat_t + ((size_t)b*NN + idxv)*32;
    #pragma unroll
    for (int h=0; h<32; h+=4){ float4 x=*(const float4*)(fb+h);
      h2[h>>1] = pkh(x.x,x.y); h2[(h>>1)+1] = pkh(x.z,x.w); }
  }
  const float* tp = xyz + bn*3;
  const float* qp = xyz + ((size_t)b*NN + idxv)*3;
  float t0=tp[0],t1=tp[1],t2=tp[2];
  float q0=qp[0],q1=qp[1],q2=qp[2];
  float r0=t0-q0,r1=t1-q1,r2=t2-q2;
  v2f e2[5] = { {sqrtf(r0*r0+r1*r1+r2*r2), r0}, {r1,r2}, {t0,t1}, {t2,q0}, {q1,q2} };

  // mlp1 (10->32, BN pre-folded, relu) — fp32 -> f16 pairs ch 32..63
  #pragma unroll
  for (int h=0; h<32; h+=2){
    const v2f* w0 = (const v2f*)(g_pw1 + h*10);
    const v2f* w1 = (const v2f*)(g_pw1 + (h+1)*10);
    v2f a0=mk2(g_pb1[h],0.f), a1=mk2(g_pb1[h+1],0.f);
    #pragma unroll
    for (int c=0; c<5; ++c){ a0=fma2(w0[c],e2[c],a0); a1=fma2(w1[c],e2[c],a1); }
    h2[16+(h>>1)] = pkh(fmaxf(a0.x+a0.y,0.f), fmaxf(a1.x+a1.y,0.f));
  }

  // fc1 (dot2, weights*log2e) + relu + exp2-softmax over K + agg — quads
  float sp4[4], sf4[4];
  #pragma unroll
  for (int ob=0; ob<64; ob+=4){
    const h16x2* w0 = &g_fch1[(ob+0)*32];
    const h16x2* w1p = &g_fch1[(ob+1)*32];
    const h16x2* w2p = &g_fch1[(ob+2)*32];
    const h16x2* w3p = &g_fch1[(ob+3)*32];
    float a0=g_fcb1s[ob+0], a1=g_fcb1s[ob+1], a2=g_fcb1s[ob+2], a3=g_fcb1s[ob+3];
    #pragma unroll
    for (int c=0; c<32; ++c){
      h16x2 f = h2[c];
      a0 = dot2acc(w0[c], f, a0); a1 = dot2acc(w1p[c], f, a1);
      a2 = dot2acc(w2p[c], f, a2); a3 = dot2acc(w3p[c], f, a3);
    }
    float p0=exp2fast(fmaxf(a0,0.f)), p1=exp2fast(fmaxf(a1,0.f));
    float p2=exp2fast(fmaxf(a2,0.f)), p3=exp2fast(fmaxf(a3,0.f));
    float f0=(float)h2[(ob>>1)+0].x, f1=(float)h2[(ob>>1)+0].y;
    float f2=(float)h2[(ob>>1)+1].x, f3=(float)h2[(ob>>1)+1].y;
    float q0v=f0*p0, q1v=f1*p1, q2v=f2*p2, q3v=f3*p3;
    float s0=red16_sum(p0), s1=red16_sum(p1), s2=red16_sum(p2), s3=red16_sum(p3);
    float t0v=red16_sum(q0v), t1v=red16_sum(q1v), t2v=red16_sum(q2v), t3v=red16_sum(q3v);
    if ((ob>>2)==k){
      sp4[0]=s0; sp4[1]=s1; sp4[2]=s2; sp4[3]=s3;
      sf4[0]=t0v; sf4[1]=t1v; sf4[2]=t2v; sf4[3]=t3v;
    }
  }
  float a0=__fdividef(sf4[0],sp4[0]), a1=__fdividef(sf4[1],sp4[1]);
  float a2=__fdividef(sf4[2],sp4[2]), a3=__fdividef(sf4[3],sp4[3]);

  // broadcast agg via per-wave LDS (lane k owns agg[4k..4k+3])
  *(float4*)&s_agg[wvv][ns][4*k] = make_float4(a0,a1,a2,a3);
  wave_sync();
  h16x2 hAg[32];
  {
    const float* ag = &s_agg[wvv][ns][0];
    #pragma unroll
    for (int c4=0;c4<16;++c4){ float4 x = *(const float4*)(ag + 4*c4);
      hAg[2*c4] = pkh(x.x,x.y); hAg[2*c4+1] = pkh(x.z,x.w); }
  }
  // ap1: lane k computes channels k and k+16 (lane-local dot2, no reductions)
  const h16x2* w0 = &g_cwh[k*32];
  const h16x2* w1 = &g_cwh[(k+16)*32];
  float o0 = g_pcb[k], o1 = g_pcb[k+16];
  #pragma unroll
  for (int c=0;c<32;++c){ o0 = dot2acc(w0[c], hAg[c], o0); o1 = dot2acc(w1[c], hAg[c], o1); }
  float* fo = fagg + bn*32;
  fo[k]    = fmaxf(o0, 0.f);
  fo[k+16] = fmaxf(o1, 0.f);
}

__global__ __launch_bounds__(256,2) void k_stage2(
  const float* __restrict__ xyz, const float* __restrict__ fagg, const int* __restrict__ nidx,
  float* __restrict__ outp)
{
  __shared__ float s_agg[4][4][64];
  int tid = threadIdx.x;
  int lane = tid & 63, wvv = tid >> 6;
  int k = lane & 15, ns = lane >> 4;
  int b = blockIdx.x / (NN/16);
  int n = (blockIdx.x % (NN/16))*16 + wvv*4 + ns;
  size_t bn = (size_t)b*NN + n;
  int idxv = nidx[bn*KK + k];

  // scattered gather first (fagg row -> f16, ch 0..31)
  h16x2 h2[32];
  {
    const float* fb = fagg + ((size_t)b*NN + idxv)*32;
    #pragma unroll
    for (int h=0; h<32; h+=4){ float4 x=*(const float4*)(fb+h);
      h2[h>>1] = pkh(x.x,x.y); h2[(h>>1)+1] = pkh(x.z,x.w); }
  }
  const float* tp = xyz + bn*3;
  const float* qp = xyz + ((size_t)b*NN + idxv)*3;
  float t0=tp[0],t1=tp[1],t2=tp[2];
  float q0=qp[0],q1=qp[1],q2=qp[2];
  float r0=t0-q0,r1=t1-q1,r2=t2-q2;
  v2f e2[5] = { {sqrtf(r0*r0+r1*r1+r2*r2), r0}, {r1,r2}, {t0,t1}, {t2,q0}, {q1,q2} };

  // recompute f_xyz (mlp1) — fp32 -> f16 pairs
  h16x2 hx[16];
  #pragma unroll
  for (int h=0; h<32; h+=2){
    const v2f* w0 = (const v2f*)(g_pw1 + h*10);
    const v2f* w1 = (const v2f*)(g_pw1 + (h+1)*10);
    v2f a0=mk2(g_pb1[h],0.f), a1=mk2(g_pb1[h+1],0.f);
    #pragma unroll
    for (int c=0; c<5; ++c){ a0=fma2(w0[c],e2[c],a0); a1=fma2(w1[c],e2[c],a1); }
    hx[h>>1] = pkh(fmaxf(a0.x+a0.y,0.f), fmaxf(a1.x+a1.y,0.f));
  }
  // mlp2 (32->32) via dot2 -> ch 32..63
  #pragma unroll
  for (int h=0; h<32; h+=2){
    const h16x2* wr0 = &g_w2h[(h+0)*16];
    const h16x2* wr1 = &g_w2h[(h+1)*16];
    float a0 = g_pb2[h+0], a1 = g_pb2[h+1];
    #pragma unroll
    for (int c=0; c<16; ++c){ h16x2 f=hx[c]; a0=dot2acc(wr0[c],f,a0); a1=dot2acc(wr1[c],f,a1); }
    h2[16+(h>>1)] = pkh(fmaxf(a0,0.f), fmaxf(a1,0.f));
  }

  // fc2 via dot2 + exp2-softmax + agg — quads
  float sp4[4], sf4[4];
  #pragma unroll
  for (int ob=0; ob<64; ob+=4){
    const h16x2* w0 = &g_fch2[(ob+0)*32];
    const h16x2* w1p = &g_fch2[(ob+1)*32];
    const h16x2* w2p = &g_fch2[(ob+2)*32];
    const h16x2* w3p = &g_fch2[(ob+3)*32];
    float a0=g_fcb2s[ob+0], a1=g_fcb2s[ob+1], a2=g_fcb2s[ob+2], a3=g_fcb2s[ob+3];
    #pragma unroll
    for (int c=0; c<32; ++c){
      h16x2 f = h2[c];
      a0 = dot2acc(w0[c], f, a0); a1 = dot2acc(w1p[c], f, a1);
      a2 = dot2acc(w2p[c], f, a2); a3 = dot2acc(w3p[c], f, a3);
    }
    float p0=exp2fast(fmaxf(a0,0.f)), p1=exp2fast(fmaxf(a1,0.f));
    float p2=exp2fast(fmaxf(a2,0.f)), p3=exp2fast(fmaxf(a3,0.f));
    float f0=(float)h2[(ob>>1)+0].x, f1=(float)h2[(ob>>1)+0].y;
    float f2=(float)h2[(ob>>1)+1].x, f3=(float)h2[(ob>>1)+1].y;
    float q0v=f0*p0, q1v=f1*p1, q2v=f2*p2, q3v=f3*p3;
    float s0=red16_sum(p0), s1=red16_sum(p1), s2=red16_sum(p2), s3=red16_sum(p3);
    float t0v=red16_sum(q0v), t1v=red16_sum(q1v), t2v=red16_sum(q2v), t3v=red16_sum(q3v);
    if ((ob>>2)==k){
      sp4[0]=s0; sp4[1]=s1; sp4[2]=s2; sp4[3]=s3;
      sf4[0]=t0v; sf4[1]=t1v; sf4[2]=t2v; sf4[3]=t3v;
    }
  }
  float a0=__fdividef(sf4[0],sp4[0]), a1=__fdividef(sf4[1],sp4[1]);
  float a2=__fdividef(sf4[2],sp4[2]), a3=__fdividef(sf4[3],sp4[3]);

  // broadcast agg via per-wave LDS
  *(float4*)&s_agg[wvv][ns][4*k] = make_float4(a0,a1,a2,a3);
  wave_sync();
  h16x2 hAg[32];
  {
    const float* ag = &s_agg[wvv][ns][0];
    #pragma unroll
    for (int c4=0;c4<16;++c4){ float4 x = *(const float4*)(ag + 4*c4);
      hAg[2*c4] = pkh(x.x,x.y); hAg[2*c4+1] = pkh(x.z,x.w); }
  }
  // ap2: lane k computes channels k+16j (lane-local dot2, no reductions)
  #pragma unroll
  for (int j=0; j<4; ++j){
    const h16x2* wr = &g_dwh[(k+16*j)*32];
    float acc = g_pdb[k+16*j];
    #pragma unroll
    for (int c=0;c<32;++c) acc = dot2acc(wr[c], hAg[c], acc);
    outp[((size_t)(b*64 + k + 16*j))*NN + n] = fmaxf(acc, 0.f);
  }
}

extern "C" void kernel_launch(void* const* d_in, const int* in_sizes, int n_in,
                              void* d_out, int out_size, void* d_ws, size_t ws_size,
                              hipStream_t stream){
  const float* xyz     = (const float*)d_in[0];
  const float* feature = (const float*)d_in[1];
  const int*   nidx    = (const int*)d_in[30];
  float* feat_t = (float*)d_ws;                       // (B,N,32)
  float* fagg   = feat_t + (size_t)BB*NN*32;          // (B,N,32)

  k_pre<<<BB*NN/256 + 1, 256, 0, stream>>>(feature, feat_t,
    (const float*)d_in[2],(const float*)d_in[3],(const float*)d_in[4],(const float*)d_in[5],
    (const float*)d_in[6],(const float*)d_in[7],
    (const float*)d_in[8],(const float*)d_in[9],
    (const float*)d_in[10],(const float*)d_in[11],(const float*)d_in[12],(const float*)d_in[13],
    (const float*)d_in[14],(const float*)d_in[15],
    (const float*)d_in[16],(const float*)d_in[17],(const float*)d_in[18],(const float*)d_in[19],
    (const float*)d_in[20],(const float*)d_in[21],
    (const float*)d_in[22],(const float*)d_in[23],
    (const float*)d_in[24],(const float*)d_in[25],(const float*)d_in[26],(const float*)d_in[27],
    (const float*)d_in[28],(const float*)d_in[29]);
  k_stage1<<<BB*NN/16, 256, 0, stream>>>(xyz, feat_t, nidx, fagg);
  k_stage2<<<BB*NN/16, 256, 0, stream>>>(xyz, fagg, nidx, (float*)d_out);
}